// Round 7
// baseline (230.846 us; speedup 1.0000x reference)
//
#include <hip/hip_runtime.h>
#include <math.h>

#define LOG2E 1.4426950408889634f

typedef __attribute__((ext_vector_type(8))) __bf16 bf16x8_t;
typedef __attribute__((ext_vector_type(8))) short short8_t;
typedef __attribute__((ext_vector_type(4))) short short4_t;
typedef __attribute__((ext_vector_type(4))) float f32x4;

static __device__ __forceinline__ short f2bf(float f){
    unsigned u = __builtin_bit_cast(unsigned, f);
    unsigned r = (u + 0x7fffu + ((u >> 16) & 1u)) >> 16;
    return (short)r;
}
static __device__ __forceinline__ float bf2f(short s){
    return __builtin_bit_cast(float, (unsigned)((unsigned short)s) << 16);
}

static __device__ __forceinline__ f32x4 mfma16(short8_t a, short8_t b, f32x4 c){
    return __builtin_amdgcn_mfma_f32_16x16x32_bf16(
        __builtin_bit_cast(bf16x8_t, a), __builtin_bit_cast(bf16x8_t, b), c, 0, 0, 0);
}

// xor-lane16 within 32-lane halves (BitMode swizzle), xor-lane32 via bpermute
static __device__ __forceinline__ float swz16(float v){
    return __builtin_bit_cast(float,
        __builtin_amdgcn_ds_swizzle(__builtin_bit_cast(int, v), 0x401F));
}
static __device__ __forceinline__ float bperm32(int addr, float v){
    return __builtin_bit_cast(float,
        __builtin_amdgcn_ds_bpermute(addr, __builtin_bit_cast(int, v)));
}

// async global->LDS, 16B per lane: LDS dest = wave-uniform base + lane*16 (HW),
// global src = per-lane pointer. Our Vf layout is fragment-linear so both match.
static __device__ __forceinline__ void gload_lds16(const void* g, void* l){
    __builtin_amdgcn_global_load_lds(
        (const __attribute__((address_space(1))) unsigned char*)g,
        (__attribute__((address_space(3))) unsigned char*)l, 16, 0, 0);
}

// ---------- K1: fused prep_w + GroupNorm (independent producers, one dispatch). ----------
// Blocks 0..63: weights -> bf16 transposed [mat][d][c] via LDS tile (verbatim R2 prep_w).
// Blocks 64..2111: per-pixel GroupNorm (G=32, 8 ch/group), write hn (B, m~=w*64+h, C) bf16
// (verbatim R2 gn_kernel with bid-64). Disjoint outputs (wT / hn), no mutual deps.
__global__ __launch_bounds__(256) void prep_gn(const float* __restrict__ w0,
    const float* __restrict__ w1, const float* __restrict__ w2,
    const float* __restrict__ w3, short* __restrict__ wT,
    const float* __restrict__ x, const float* __restrict__ gnw,
    const float* __restrict__ gnb, short* __restrict__ hn)
{
    __shared__ float T[64 * 65];
    if (blockIdx.x < 64){
        const int mat = blockIdx.x >> 4, tile = blockIdx.x & 15;
        const int c0 = (tile >> 2) * 64, d0 = (tile & 3) * 64;
        const float* src = mat == 0 ? w0 : mat == 1 ? w1 : mat == 2 ? w2 : w3;
        const int t = threadIdx.x;
        #pragma unroll
        for (int i = 0; i < 4; i++){
            int r = (t >> 4) + i * 16, c4 = (t & 15) * 4;
            f32x4 v = *(const f32x4*)(src + (size_t)(c0 + r) * 256 + d0 + c4);
            #pragma unroll
            for (int j = 0; j < 4; j++) T[r * 65 + c4 + j] = v[j];
        }
        __syncthreads();
        int drow = t >> 2, cb = (t & 3) * 16;
        short tmp[16];
        #pragma unroll
        for (int j = 0; j < 16; j++) tmp[j] = f2bf(T[(cb + j) * 65 + drow]);
        short* dst = wT + (size_t)mat * 65536 + (size_t)(d0 + drow) * 256 + c0 + cb;
        *(short8_t*)dst = *(short8_t*)tmp;
        *(short8_t*)(dst + 8) = *(short8_t*)(tmp + 8);
    } else {
        int flat = (blockIdx.x - 64) * 256 + threadIdx.x;
        int n = flat & 4095, g = (flat >> 12) & 31, b = flat >> 17;
        const float* xp = x + (size_t)(b * 256 + g * 8) * 4096 + n;
        float v[8], s = 0.f, s2 = 0.f;
        #pragma unroll
        for (int k = 0; k < 8; k++){ float t = xp[(size_t)k * 4096]; v[k] = t; s += t; s2 += t * t; }
        float mean = s * 0.125f;
        float var  = s2 * 0.125f - mean * mean;
        float inv  = rsqrtf(var + 1e-6f);
        int h = n >> 6, w = n & 63, m = w * 64 + h;
        short o[8];
        #pragma unroll
        for (int k = 0; k < 8; k++)
            o[k] = f2bf((v[k] - mean) * inv * gnw[g * 8 + k] + gnb[g * 8 + k]);
        *(short8_t*)(hn + (size_t)(b * 4096 + m) * 256 + g * 8) = *(short8_t*)o;
    }
}

// ---------- K3: QKV GEMM (R2-exact split: grid 256x12). Q row-major (pre-scaled 1/16);
// K,V fragment-major.
// Kf[(b,kb64,kc,ks,lane,8)]: lane holds key kc*16+(lane&15), ch ks*32+(lane>>4)*8+j.
// Vf2[(b,kbd,kc,cht,lane,8)]: lane holds ch cht*16+(lane&15); j<4: key kbd*128+kc*16+(lane>>4)*4+j,
//                             j>=4: key kbd*128+64+kc*16+(lane>>4)*4+(j-4).  (K=32 PV permutation)
__global__ __launch_bounds__(256) void qkv_gemm(const short* __restrict__ hn,
    const short* __restrict__ wT, const float* __restrict__ bq,
    const float* __restrict__ bk, const float* __restrict__ bv,
    short* __restrict__ Q, short* __restrict__ Kf, short* __restrict__ Vf)
{
    __shared__ short As[64 * 72];
    __shared__ short Bs[64 * 72];
    __shared__ float CT[64 * 65];

    const int tid = threadIdx.x;
    const int m0 = blockIdx.x * 64;
    const int by = blockIdx.y;
    const int mat = by >> 2;                 // 0=Q 1=K 2=V
    const int d0 = (by & 3) * 64;
    const short* w = wT + mat * 65536;
    const float* bias = mat == 0 ? bq : mat == 1 ? bk : bv;

    const int wv = tid >> 6, lane = tid & 63;
    const int wrow = (wv >> 1) * 32, wcol = (wv & 1) * 32;
    const int lrow = lane & 15, lq = lane >> 4;

    f32x4 acc[2][2] = {};

    for (int k0 = 0; k0 < 256; k0 += 64){
        __syncthreads();
        #pragma unroll
        for (int i = 0; i < 2; i++){
            int idx = tid + i * 256, r = idx >> 3, c = (idx & 7) * 8;
            *(short8_t*)&As[r * 72 + c] = *(const short8_t*)(hn + (size_t)(m0 + r) * 256 + k0 + c);
            *(short8_t*)&Bs[r * 72 + c] = *(const short8_t*)(w  + (size_t)(d0 + r) * 256 + k0 + c);
        }
        __syncthreads();
        #pragma unroll
        for (int kk = 0; kk < 2; kk++){
            int off = kk * 32 + lq * 8;
            short8_t a0  = *(short8_t*)&As[(wrow + lrow) * 72 + off];
            short8_t a1  = *(short8_t*)&As[(wrow + 16 + lrow) * 72 + off];
            short8_t b0v = *(short8_t*)&Bs[(wcol + lrow) * 72 + off];
            short8_t b1v = *(short8_t*)&Bs[(wcol + 16 + lrow) * 72 + off];
            acc[0][0] = mfma16(a0, b0v, acc[0][0]);
            acc[0][1] = mfma16(a0, b1v, acc[0][1]);
            acc[1][0] = mfma16(a1, b0v, acc[1][0]);
            acc[1][1] = mfma16(a1, b1v, acc[1][1]);
        }
    }

    const int b = m0 >> 12, kb64 = (m0 & 4095) >> 6;

    if (mat == 0){
        #pragma unroll
        for (int i = 0; i < 2; i++)
          #pragma unroll
          for (int j = 0; j < 2; j++)
            #pragma unroll
            for (int r = 0; r < 4; r++){
                int row = wrow + i * 16 + lq * 4 + r;
                int col = wcol + j * 16 + lrow;
                Q[(size_t)(m0 + row) * 256 + d0 + col] = f2bf((acc[i][j][r] + bias[d0 + col]) * 0.0625f);
            }
    } else if (mat == 1){
        // CT[key][ch]
        #pragma unroll
        for (int i = 0; i < 2; i++)
          #pragma unroll
          for (int j = 0; j < 2; j++)
            #pragma unroll
            for (int r = 0; r < 4; r++){
                int row = wrow + i * 16 + lq * 4 + r;
                int col = wcol + j * 16 + lrow;
                CT[row * 65 + col] = acc[i][j][r] + bias[d0 + col];
            }
        __syncthreads();
        int key = tid >> 2, c16 = (tid & 3) * 16;
        int kc = key >> 4, l15 = key & 15;
        #pragma unroll
        for (int half = 0; half < 2; half++){
            int ch0 = c16 + half * 8;
            int ks = (d0 + ch0) >> 5, lqf = (ch0 & 31) >> 3;
            short tmp[8];
            #pragma unroll
            for (int j = 0; j < 8; j++) tmp[j] = f2bf(CT[key * 65 + ch0 + j]);
            size_t base = ((((size_t)(b * 64 + kb64)) * 4 + kc) * 8 + ks) * 512 + (lqf * 16 + l15) * 8;
            *(short8_t*)(Kf + base) = *(short8_t*)tmp;
        }
    } else {
        // CT[ch][key]
        #pragma unroll
        for (int i = 0; i < 2; i++)
          #pragma unroll
          for (int j = 0; j < 2; j++)
            #pragma unroll
            for (int r = 0; r < 4; r++){
                int row = wrow + i * 16 + lq * 4 + r;
                int col = wcol + j * 16 + lrow;
                CT[col * 65 + row] = acc[i][j][r] + bias[d0 + col];
            }
        __syncthreads();
        const int kbd = kb64 >> 1, parity = kb64 & 1;
        const int cht_l = tid >> 6, lane_s = tid & 63;
        const int l15s = lane_s & 15, lg4s = lane_s >> 4;
        const int cht = (d0 >> 4) + cht_l;
        #pragma unroll
        for (int kc = 0; kc < 4; kc++){
            short tmp[4];
            #pragma unroll
            for (int j = 0; j < 4; j++)
                tmp[j] = f2bf(CT[(cht_l * 16 + l15s) * 65 + kc * 16 + lg4s * 4 + j]);
            size_t base = (size_t)b * 1048576 + (size_t)kbd * 32768 + kc * 8192
                        + cht * 512 + lane_s * 8 + parity * 4;
            *(short4_t*)(Vf + base) = *(short4_t*)tmp;
        }
    }
}

// ---------- K4: flash attention (R2 structure + register-neutral latency package):
// 32 queries/wave, lean softmax (defer-max THR=5, per-lane l partials), V staged via
// global_load_lds, next-K reg prefetch, XCD batch affinity, (w,63-w) grid pairing.
// NEW vs R2: (a) QK accumulation chains split 8 -> 4+4 (4 independent MFMA chains per
// strip, combined with f32 adds) to hide MFMA dependent-accumulate latency;
// (b) s_setprio(1) around MFMA clusters (T5; independent-block regime per m191).
// Register budget is at the 256/wave cliff (VGPR 128 + AGPR 128): split temporaries
// reuse the pA/pB dead range (disjoint lifetimes) — spill tripwire is WRITE_SIZE.
__global__ __launch_bounds__(256, 2) void attn_kernel(const short* __restrict__ Q,
    const short* __restrict__ Kf, const short* __restrict__ Vf,
    short* __restrict__ hb)
{
    __shared__ short SH[4 * 32 * 264];   // 67.6KB: V stage (first 64KB) during loop, LOs after
    __shared__ float mls[4][32][2];

    const int tid = threadIdx.x, lane = tid & 63, kc = tid >> 6;
    const int l15 = lane & 15, lg4 = lane >> 4;
    const int a32 = ((lane ^ 32) << 2);

    const int id  = blockIdx.x;
    const int xcd = id & 7;
    const int b   = xcd >> 1;
    const int hh  = xcd & 1;
    const int r_  = id >> 3;
    const int t_  = r_ & 31;
    const int w   = (r_ & 32) ? 63 - t_ : t_;
    const int q0  = w * 64 + hh * 32;        // tile0: q0+l15, tile1: q0+16+l15

    const short* Kb = Kf + (size_t)b * 1048576 + kc * 4096 + lane * 8;   // +kb*16384 +ks*512
    const short* Vg = Vf + (size_t)b * 1048576 + kc * 8192 + lane * 8;   // per-lane V src
    short* Vl = &SH[kc * 8192];                                          // wave LDS V slice

    // Q as B-fragment (pre-scaled): lane holds Q[q][ks*32+lg4*8 ..+8]
    short8_t qf0[8], qf1[8];
    {
        const short* qp0 = Q + ((size_t)b * 4096 + q0 + l15) * 256;
        const short* qp1 = qp0 + 16 * 256;
        #pragma unroll
        for (int ks = 0; ks < 8; ks++){
            qf0[ks] = *(const short8_t*)(qp0 + ks * 32 + lg4 * 8);
            qf1[ks] = *(const short8_t*)(qp1 + ks * 32 + lg4 * 8);
        }
    }

    f32x4 oacc0[16] = {}, oacc1[16] = {};
    float m0 = -1e30f, l0 = 0.f;             // l0,l1 are PER-LANE partial sums
    float m1 = -1e30f, l1 = 0.f;

    short8_t kf[8];
    #pragma unroll
    for (int ks = 0; ks < 8; ks++) kf[ks] = *(const short8_t*)(Kb + ks * 512);

    for (int kb = 0; kb <= w; kb += 2){
        const bool has_odd = (kb + 1 <= w);

        // strip A QK (kf holds strip kb): 4 independent 4-deep chains
        f32x4 stA0, stA1;
        {
            f32x4 sa0 = {}, sb0 = {}, sa1 = {}, sb1 = {};
            __builtin_amdgcn_s_setprio(1);
            #pragma unroll
            for (int ks = 0; ks < 4; ks++){
                sa0 = mfma16(kf[ks],     qf0[ks],     sa0);
                sa1 = mfma16(kf[ks],     qf1[ks],     sa1);
                sb0 = mfma16(kf[ks + 4], qf0[ks + 4], sb0);
                sb1 = mfma16(kf[ks + 4], qf1[ks + 4], sb1);
            }
            __builtin_amdgcn_s_setprio(0);
            #pragma unroll
            for (int r = 0; r < 4; r++){
                stA0[r] = sa0[r] + sb0[r];
                stA1[r] = sa1[r] + sb1[r];
            }
        }
        // strip B loads into kf (WAR after stA issue)
        if (has_odd){
            const short* ka = Kb + (size_t)(kb + 1) * 16384;
            #pragma unroll
            for (int ks = 0; ks < 8; ks++) kf[ks] = *(const short8_t*)(ka + ks * 512);
        }
        // V stage for this pair (async -> LDS, newest vmem ops)
        {
            const short* vsrc = Vg + (size_t)(kb >> 1) * 32768;
            #pragma unroll
            for (int i = 0; i < 16; i++)
                gload_lds16(vsrc + i * 512, Vl + i * 512);
        }

        // lean softmax A (covers strip-B load latency)
        f32x4 pA0, pA1;
        {
            float tl0 = fmaxf(fmaxf(stA0[0], stA0[1]), fmaxf(stA0[2], stA0[3]));
            float tl1 = fmaxf(fmaxf(stA1[0], stA1[1]), fmaxf(stA1[2], stA1[3]));
            if (!__all(tl0 <= m0 + 5.f && tl1 <= m1 + 5.f)){
                float tm0 = fmaxf(tl0, swz16(tl0)); tm0 = fmaxf(tm0, bperm32(a32, tm0));
                float tm1 = fmaxf(tl1, swz16(tl1)); tm1 = fmaxf(tm1, bperm32(a32, tm1));
                float mn0 = fmaxf(m0, tm0), mn1 = fmaxf(m1, tm1);
                float al0 = exp2f((m0 - mn0) * LOG2E), al1 = exp2f((m1 - mn1) * LOG2E);
                l0 *= al0; l1 *= al1;
                #pragma unroll
                for (int i = 0; i < 16; i++){
                    #pragma unroll
                    for (int r = 0; r < 4; r++){ oacc0[i][r] *= al0; oacc1[i][r] *= al1; }
                }
                m0 = mn0; m1 = mn1;
            }
            #pragma unroll
            for (int r = 0; r < 4; r++){
                pA0[r] = exp2f((stA0[r] - m0) * LOG2E);
                pA1[r] = exp2f((stA1[r] - m1) * LOG2E);
            }
            l0 += (pA0[0] + pA0[1]) + (pA0[2] + pA0[3]);
            l1 += (pA1[0] + pA1[1]) + (pA1[2] + pA1[3]);
        }

        // strip B QK (4 independent chains) + next-pair strip-A prefetch + lean softmax B
        f32x4 pB0 = {0.f, 0.f, 0.f, 0.f}, pB1 = {0.f, 0.f, 0.f, 0.f};
        if (has_odd){
            f32x4 stB0, stB1;
            {
                f32x4 sa0 = {}, sb0 = {}, sa1 = {}, sb1 = {};
                __builtin_amdgcn_s_setprio(1);
                #pragma unroll
                for (int ks = 0; ks < 4; ks++){
                    sa0 = mfma16(kf[ks],     qf0[ks],     sa0);
                    sa1 = mfma16(kf[ks],     qf1[ks],     sa1);
                    sb0 = mfma16(kf[ks + 4], qf0[ks + 4], sb0);
                    sb1 = mfma16(kf[ks + 4], qf1[ks + 4], sb1);
                }
                __builtin_amdgcn_s_setprio(0);
                #pragma unroll
                for (int r = 0; r < 4; r++){
                    stB0[r] = sa0[r] + sb0[r];
                    stB1[r] = sa1[r] + sb1[r];
                }
            }
            if (kb + 2 <= w){
                const short* ka = Kb + (size_t)(kb + 2) * 16384;
                #pragma unroll
                for (int ks = 0; ks < 8; ks++) kf[ks] = *(const short8_t*)(ka + ks * 512);
            }
            float tl0 = fmaxf(fmaxf(stB0[0], stB0[1]), fmaxf(stB0[2], stB0[3]));
            float tl1 = fmaxf(fmaxf(stB1[0], stB1[1]), fmaxf(stB1[2], stB1[3]));
            if (!__all(tl0 <= m0 + 5.f && tl1 <= m1 + 5.f)){
                float tm0 = fmaxf(tl0, swz16(tl0)); tm0 = fmaxf(tm0, bperm32(a32, tm0));
                float tm1 = fmaxf(tl1, swz16(tl1)); tm1 = fmaxf(tm1, bperm32(a32, tm1));
                float mn0 = fmaxf(m0, tm0), mn1 = fmaxf(m1, tm1);
                float al0 = exp2f((m0 - mn0) * LOG2E), al1 = exp2f((m1 - mn1) * LOG2E);
                l0 *= al0; l1 *= al1;
                #pragma unroll
                for (int i = 0; i < 16; i++){
                    #pragma unroll
                    for (int r = 0; r < 4; r++){ oacc0[i][r] *= al0; oacc1[i][r] *= al1; }
                }
                #pragma unroll
                for (int r = 0; r < 4; r++){ pA0[r] *= al0; pA1[r] *= al1; }
                m0 = mn0; m1 = mn1;
            }
            #pragma unroll
            for (int r = 0; r < 4; r++){
                pB0[r] = exp2f((stB0[r] - m0) * LOG2E);
                pB1[r] = exp2f((stB1[r] - m1) * LOG2E);
            }
            l0 += (pB0[0] + pB0[1]) + (pB0[2] + pB0[3]);
            l1 += (pB1[0] + pB1[1]) + (pB1[2] + pB1[3]);
        }

        // pack P^T pair as B-fragment (K=32, key-permuted to match Vf2)
        short pk0[8], pk1[8];
        #pragma unroll
        for (int r = 0; r < 4; r++){
            pk0[r] = f2bf(pA0[r]); pk0[4 + r] = f2bf(pB0[r]);
            pk1[r] = f2bf(pA1[r]); pk1[4 + r] = f2bf(pB1[r]);
        }
        short8_t pbf0 = *(short8_t*)pk0;
        short8_t pbf1 = *(short8_t*)pk1;

        // wait V in LDS: if next-A prefetch (8 loads) is newest, vmcnt(8) drains all V;
        // otherwise nothing was issued after V -> drain fully.
        if (kb + 2 <= w){
            asm volatile("s_waitcnt vmcnt(8)" ::: "memory");
        } else {
            asm volatile("s_waitcnt vmcnt(0)" ::: "memory");
        }
        // PV from LDS (conflict-free linear ds_read_b128)
        __builtin_amdgcn_s_setprio(1);
        #pragma unroll
        for (int cht = 0; cht < 16; cht++){
            short8_t vfr = *(const short8_t*)(Vl + cht * 512 + lane * 8);
            oacc0[cht] = mfma16(vfr, pbf0, oacc0[cht]);
            oacc1[cht] = mfma16(vfr, pbf1, oacc1[cht]);
        }
        __builtin_amdgcn_s_setprio(0);
    }

    // ---- reduce per-lane l partials across the 4 lanes of each query ----
    float l0t = l0 + swz16(l0); l0t += bperm32(a32, l0t);
    float l1t = l1 + swz16(l1); l1t += bperm32(a32, l1t);

    // ---- combine the 4 kc partials ----
    if (lg4 == 0){
        mls[kc][l15][0] = m0;      mls[kc][l15][1] = l0t;
        mls[kc][16 + l15][0] = m1; mls[kc][16 + l15][1] = l1t;
    }
    __syncthreads();
    float sc0, sc1;
    {
        float ms0 = fmaxf(fmaxf(mls[0][l15][0], mls[1][l15][0]),
                          fmaxf(mls[2][l15][0], mls[3][l15][0]));
        float ms1 = fmaxf(fmaxf(mls[0][16 + l15][0], mls[1][16 + l15][0]),
                          fmaxf(mls[2][16 + l15][0], mls[3][16 + l15][0]));
        sc0 = exp2f((m0 - ms0) * LOG2E);
        sc1 = exp2f((m1 - ms1) * LOG2E);
    }
    #pragma unroll
    for (int cht = 0; cht < 16; cht++){
        short t4[4];
        #pragma unroll
        for (int r = 0; r < 4; r++) t4[r] = f2bf(oacc0[cht][r] * sc0);
        *(short4_t*)&SH[((kc * 32) + l15) * 264 + cht * 16 + lg4 * 4] = *(short4_t*)t4;
        #pragma unroll
        for (int r = 0; r < 4; r++) t4[r] = f2bf(oacc1[cht][r] * sc1);
        *(short4_t*)&SH[((kc * 32) + 16 + l15) * 264 + cht * 16 + lg4 * 4] = *(short4_t*)t4;
    }
    __syncthreads();
    // reduce across kc: thread -> (query qq, 32-ch chunk cc)
    {
        const int qq = tid & 31, cc = tid >> 5;
        float mv0 = mls[0][qq][0], mv1 = mls[1][qq][0], mv2 = mls[2][qq][0], mv3 = mls[3][qq][0];
        float ms = fmaxf(fmaxf(mv0, mv1), fmaxf(mv2, mv3));
        float Ls = mls[0][qq][1] * exp2f((mv0 - ms) * LOG2E)
                 + mls[1][qq][1] * exp2f((mv1 - ms) * LOG2E)
                 + mls[2][qq][1] * exp2f((mv2 - ms) * LOG2E)
                 + mls[3][qq][1] * exp2f((mv3 - ms) * LOG2E);
        float inv = 1.f / Ls;
        const int h = hh * 32 + qq;
        short* dst = hb + ((size_t)b * 4096 + h * 64 + w) * 256 + cc * 32;
        #pragma unroll
        for (int c8 = 0; c8 < 4; c8++){
            short8_t a0 = *(const short8_t*)&SH[((0 * 32) + qq) * 264 + cc * 32 + c8 * 8];
            short8_t a1 = *(const short8_t*)&SH[((1 * 32) + qq) * 264 + cc * 32 + c8 * 8];
            short8_t a2 = *(const short8_t*)&SH[((2 * 32) + qq) * 264 + cc * 32 + c8 * 8];
            short8_t a3 = *(const short8_t*)&SH[((3 * 32) + qq) * 264 + cc * 32 + c8 * 8];
            short t8[8];
            #pragma unroll
            for (int j = 0; j < 8; j++){
                float s = (bf2f(a0[j]) + bf2f(a1[j])) + (bf2f(a2[j]) + bf2f(a3[j]));
                t8[j] = f2bf(s * inv);
            }
            *(short8_t*)(dst + c8 * 8) = *(short8_t*)t8;
        }
    }
}

// ---------- K5: final proj + bias + residual (R2-exact split: grid 256x4),
// coalesced f32 store to (B,C,H,W) ----------
__global__ __launch_bounds__(256) void final_gemm(const short* __restrict__ hbuf,
    const short* __restrict__ wT3, const float* __restrict__ b3,
    const float* __restrict__ x, float* __restrict__ out)
{
    __shared__ short As[64 * 72];
    __shared__ short Bs[64 * 72];
    __shared__ float CT[64 * 65];

    const int tid = threadIdx.x;
    const int m0 = blockIdx.x * 64;
    const int d0 = blockIdx.y * 64;
    const int wv = tid >> 6, lane = tid & 63;
    const int wrow = (wv >> 1) * 32, wcol = (wv & 1) * 32;
    const int lrow = lane & 15, lq = lane >> 4;

    f32x4 acc[2][2] = {};
    for (int k0 = 0; k0 < 256; k0 += 64){
        __syncthreads();
        #pragma unroll
        for (int i = 0; i < 2; i++){
            int idx = tid + i * 256, r = idx >> 3, c = (idx & 7) * 8;
            *(short8_t*)&As[r * 72 + c] = *(const short8_t*)(hbuf + (size_t)(m0 + r) * 256 + k0 + c);
            *(short8_t*)&Bs[r * 72 + c] = *(const short8_t*)(wT3 + (size_t)(d0 + r) * 256 + k0 + c);
        }
        __syncthreads();
        #pragma unroll
        for (int kk = 0; kk < 2; kk++){
            int off = kk * 32 + lq * 8;
            short8_t a0  = *(short8_t*)&As[(wrow + lrow) * 72 + off];
            short8_t a1  = *(short8_t*)&As[(wrow + 16 + lrow) * 72 + off];
            short8_t b0v = *(short8_t*)&Bs[(wcol + lrow) * 72 + off];
            short8_t b1v = *(short8_t*)&Bs[(wcol + 16 + lrow) * 72 + off];
            acc[0][0] = mfma16(a0, b0v, acc[0][0]);
            acc[0][1] = mfma16(a0, b1v, acc[0][1]);
            acc[1][0] = mfma16(a1, b0v, acc[1][0]);
            acc[1][1] = mfma16(a1, b1v, acc[1][1]);
        }
    }
    #pragma unroll
    for (int i = 0; i < 2; i++)
      #pragma unroll
      for (int j = 0; j < 2; j++)
        #pragma unroll
        for (int r = 0; r < 4; r++){
            int row = wrow + i * 16 + lq * 4 + r;
            int col = wcol + j * 16 + lrow;
            CT[col * 65 + row] = acc[i][j][r] + b3[d0 + col];
        }
    __syncthreads();
    int b = m0 >> 12, n0 = m0 & 4095, hrow = n0 >> 6;
    int dr = tid >> 2, wc = (tid & 3) * 16;
    size_t base = ((size_t)(b * 256 + d0 + dr) * 64 + hrow) * 64 + wc;
    const f32x4* xp = (const f32x4*)(x + base);
    f32x4* op = (f32x4*)(out + base);
    #pragma unroll
    for (int q = 0; q < 4; q++){
        f32x4 xv = xp[q], o;
        #pragma unroll
        for (int j = 0; j < 4; j++) o[j] = xv[j] + CT[dr * 65 + wc + q * 4 + j];
        op[q] = o;
    }
}

extern "C" void kernel_launch(void* const* d_in, const int* in_sizes, int n_in,
                              void* d_out, int out_size, void* d_ws, size_t ws_size,
                              hipStream_t stream)
{
    const float* x   = (const float*)d_in[0];
    const float* gnw = (const float*)d_in[1];
    const float* gnb = (const float*)d_in[2];
    const float* w0  = (const float*)d_in[3];
    const float* b0  = (const float*)d_in[4];
    const float* w1  = (const float*)d_in[5];
    const float* b1  = (const float*)d_in[6];
    const float* w2  = (const float*)d_in[7];
    const float* b2  = (const float*)d_in[8];
    const float* w3  = (const float*)d_in[9];
    const float* b3  = (const float*)d_in[10];
    float* out = (float*)d_out;

    char* ws = (char*)d_ws;
    short* wT  = (short*)(ws);                  // 512 KB
    short* hn  = (short*)(ws + 524288);         // 8 MB
    short* Qb  = (short*)(ws + 8912896);        // 8 MB
    short* Kfb = (short*)(ws + 17301504);       // frag-major K, 8 MB
    short* Vfb = (short*)(ws + 25690112);       // frag-major V (K=32 perm), 8 MB
    short* hb  = (short*)(ws + 34078720);       // (B, n, C) 8 MB

    prep_gn  <<<2112, 256, 0, stream>>>(w0, w1, w2, w3, wT, x, gnw, gnb, hn);
    qkv_gemm <<<dim3(256, 12), 256, 0, stream>>>(hn, wT, b0, b1, b2, Qb, Kfb, Vfb);
    attn_kernel<<<512, 256, 0, stream>>>(Qb, Kfb, Vfb, hb);
    final_gemm<<<dim3(256, 4), 256, 0, stream>>>(hb, wT + 3 * 65536, b3, x, out);
}

// Round 8
// 198.725 us; speedup vs baseline: 1.1616x; 1.1616x over previous
//
#include <hip/hip_runtime.h>
#include <math.h>

#define LOG2E 1.4426950408889634f

typedef __attribute__((ext_vector_type(8))) __bf16 bf16x8_t;
typedef __attribute__((ext_vector_type(8))) short short8_t;
typedef __attribute__((ext_vector_type(4))) short short4_t;
typedef __attribute__((ext_vector_type(4))) float f32x4;

static __device__ __forceinline__ short f2bf(float f){
    unsigned u = __builtin_bit_cast(unsigned, f);
    unsigned r = (u + 0x7fffu + ((u >> 16) & 1u)) >> 16;
    return (short)r;
}
static __device__ __forceinline__ float bf2f(short s){
    return __builtin_bit_cast(float, (unsigned)((unsigned short)s) << 16);
}

static __device__ __forceinline__ f32x4 mfma16(short8_t a, short8_t b, f32x4 c){
    return __builtin_amdgcn_mfma_f32_16x16x32_bf16(
        __builtin_bit_cast(bf16x8_t, a), __builtin_bit_cast(bf16x8_t, b), c, 0, 0, 0);
}

// xor-lane16 within 32-lane halves (BitMode swizzle), xor-lane32 via bpermute
static __device__ __forceinline__ float swz16(float v){
    return __builtin_bit_cast(float,
        __builtin_amdgcn_ds_swizzle(__builtin_bit_cast(int, v), 0x401F));
}
static __device__ __forceinline__ float bperm32(int addr, float v){
    return __builtin_bit_cast(float,
        __builtin_amdgcn_ds_bpermute(addr, __builtin_bit_cast(int, v)));
}

// async global->LDS, 16B per lane: LDS dest = wave-uniform base + lane*16 (HW),
// global src = per-lane pointer. Our Vf layout is fragment-linear so both match.
static __device__ __forceinline__ void gload_lds16(const void* g, void* l){
    __builtin_amdgcn_global_load_lds(
        (const __attribute__((address_space(1))) unsigned char*)g,
        (__attribute__((address_space(3))) unsigned char*)l, 16, 0, 0);
}

// ---------- K1: fused prep_w + GroupNorm (independent producers, one dispatch). ----------
// Blocks 0..63: weights -> bf16 transposed [mat][d][c] via LDS tile (verbatim R2 prep_w).
// Blocks 64..2111: per-pixel GroupNorm (G=32, 8 ch/group), write hn (B, m~=w*64+h, C) bf16
// (verbatim R2 gn_kernel with bid-64). Disjoint outputs (wT / hn), no mutual deps.
__global__ __launch_bounds__(256) void prep_gn(const float* __restrict__ w0,
    const float* __restrict__ w1, const float* __restrict__ w2,
    const float* __restrict__ w3, short* __restrict__ wT,
    const float* __restrict__ x, const float* __restrict__ gnw,
    const float* __restrict__ gnb, short* __restrict__ hn)
{
    __shared__ float T[64 * 65];
    if (blockIdx.x < 64){
        const int mat = blockIdx.x >> 4, tile = blockIdx.x & 15;
        const int c0 = (tile >> 2) * 64, d0 = (tile & 3) * 64;
        const float* src = mat == 0 ? w0 : mat == 1 ? w1 : mat == 2 ? w2 : w3;
        const int t = threadIdx.x;
        #pragma unroll
        for (int i = 0; i < 4; i++){
            int r = (t >> 4) + i * 16, c4 = (t & 15) * 4;
            f32x4 v = *(const f32x4*)(src + (size_t)(c0 + r) * 256 + d0 + c4);
            #pragma unroll
            for (int j = 0; j < 4; j++) T[r * 65 + c4 + j] = v[j];
        }
        __syncthreads();
        int drow = t >> 2, cb = (t & 3) * 16;
        short tmp[16];
        #pragma unroll
        for (int j = 0; j < 16; j++) tmp[j] = f2bf(T[(cb + j) * 65 + drow]);
        short* dst = wT + (size_t)mat * 65536 + (size_t)(d0 + drow) * 256 + c0 + cb;
        *(short8_t*)dst = *(short8_t*)tmp;
        *(short8_t*)(dst + 8) = *(short8_t*)(tmp + 8);
    } else {
        int flat = (blockIdx.x - 64) * 256 + threadIdx.x;
        int n = flat & 4095, g = (flat >> 12) & 31, b = flat >> 17;
        const float* xp = x + (size_t)(b * 256 + g * 8) * 4096 + n;
        float v[8], s = 0.f, s2 = 0.f;
        #pragma unroll
        for (int k = 0; k < 8; k++){ float t = xp[(size_t)k * 4096]; v[k] = t; s += t; s2 += t * t; }
        float mean = s * 0.125f;
        float var  = s2 * 0.125f - mean * mean;
        float inv  = rsqrtf(var + 1e-6f);
        int h = n >> 6, w = n & 63, m = w * 64 + h;
        short o[8];
        #pragma unroll
        for (int k = 0; k < 8; k++)
            o[k] = f2bf((v[k] - mean) * inv * gnw[g * 8 + k] + gnb[g * 8 + k]);
        *(short8_t*)(hn + (size_t)(b * 4096 + m) * 256 + g * 8) = *(short8_t*)o;
    }
}

// ---------- K3: QKV GEMM (R2-exact split: grid 256x12). Q row-major (pre-scaled 1/16);
// K,V fragment-major.
// Kf[(b,kb64,kc,ks,lane,8)]: lane holds key kc*16+(lane&15), ch ks*32+(lane>>4)*8+j.
// Vf2[(b,kbd,kc,cht,lane,8)]: lane holds ch cht*16+(lane&15); j<4: key kbd*128+kc*16+(lane>>4)*4+j,
//                             j>=4: key kbd*128+64+kc*16+(lane>>4)*4+(j-4).  (K=32 PV permutation)
__global__ __launch_bounds__(256) void qkv_gemm(const short* __restrict__ hn,
    const short* __restrict__ wT, const float* __restrict__ bq,
    const float* __restrict__ bk, const float* __restrict__ bv,
    short* __restrict__ Q, short* __restrict__ Kf, short* __restrict__ Vf)
{
    __shared__ short As[64 * 72];
    __shared__ short Bs[64 * 72];
    __shared__ float CT[64 * 65];

    const int tid = threadIdx.x;
    const int m0 = blockIdx.x * 64;
    const int by = blockIdx.y;
    const int mat = by >> 2;                 // 0=Q 1=K 2=V
    const int d0 = (by & 3) * 64;
    const short* w = wT + mat * 65536;
    const float* bias = mat == 0 ? bq : mat == 1 ? bk : bv;

    const int wv = tid >> 6, lane = tid & 63;
    const int wrow = (wv >> 1) * 32, wcol = (wv & 1) * 32;
    const int lrow = lane & 15, lq = lane >> 4;

    f32x4 acc[2][2] = {};

    for (int k0 = 0; k0 < 256; k0 += 64){
        __syncthreads();
        #pragma unroll
        for (int i = 0; i < 2; i++){
            int idx = tid + i * 256, r = idx >> 3, c = (idx & 7) * 8;
            *(short8_t*)&As[r * 72 + c] = *(const short8_t*)(hn + (size_t)(m0 + r) * 256 + k0 + c);
            *(short8_t*)&Bs[r * 72 + c] = *(const short8_t*)(w  + (size_t)(d0 + r) * 256 + k0 + c);
        }
        __syncthreads();
        #pragma unroll
        for (int kk = 0; kk < 2; kk++){
            int off = kk * 32 + lq * 8;
            short8_t a0  = *(short8_t*)&As[(wrow + lrow) * 72 + off];
            short8_t a1  = *(short8_t*)&As[(wrow + 16 + lrow) * 72 + off];
            short8_t b0v = *(short8_t*)&Bs[(wcol + lrow) * 72 + off];
            short8_t b1v = *(short8_t*)&Bs[(wcol + 16 + lrow) * 72 + off];
            acc[0][0] = mfma16(a0, b0v, acc[0][0]);
            acc[0][1] = mfma16(a0, b1v, acc[0][1]);
            acc[1][0] = mfma16(a1, b0v, acc[1][0]);
            acc[1][1] = mfma16(a1, b1v, acc[1][1]);
        }
    }

    const int b = m0 >> 12, kb64 = (m0 & 4095) >> 6;

    if (mat == 0){
        #pragma unroll
        for (int i = 0; i < 2; i++)
          #pragma unroll
          for (int j = 0; j < 2; j++)
            #pragma unroll
            for (int r = 0; r < 4; r++){
                int row = wrow + i * 16 + lq * 4 + r;
                int col = wcol + j * 16 + lrow;
                Q[(size_t)(m0 + row) * 256 + d0 + col] = f2bf((acc[i][j][r] + bias[d0 + col]) * 0.0625f);
            }
    } else if (mat == 1){
        // CT[key][ch]
        #pragma unroll
        for (int i = 0; i < 2; i++)
          #pragma unroll
          for (int j = 0; j < 2; j++)
            #pragma unroll
            for (int r = 0; r < 4; r++){
                int row = wrow + i * 16 + lq * 4 + r;
                int col = wcol + j * 16 + lrow;
                CT[row * 65 + col] = acc[i][j][r] + bias[d0 + col];
            }
        __syncthreads();
        int key = tid >> 2, c16 = (tid & 3) * 16;
        int kc = key >> 4, l15 = key & 15;
        #pragma unroll
        for (int half = 0; half < 2; half++){
            int ch0 = c16 + half * 8;
            int ks = (d0 + ch0) >> 5, lqf = (ch0 & 31) >> 3;
            short tmp[8];
            #pragma unroll
            for (int j = 0; j < 8; j++) tmp[j] = f2bf(CT[key * 65 + ch0 + j]);
            size_t base = ((((size_t)(b * 64 + kb64)) * 4 + kc) * 8 + ks) * 512 + (lqf * 16 + l15) * 8;
            *(short8_t*)(Kf + base) = *(short8_t*)tmp;
        }
    } else {
        // CT[ch][key]
        #pragma unroll
        for (int i = 0; i < 2; i++)
          #pragma unroll
          for (int j = 0; j < 2; j++)
            #pragma unroll
            for (int r = 0; r < 4; r++){
                int row = wrow + i * 16 + lq * 4 + r;
                int col = wcol + j * 16 + lrow;
                CT[col * 65 + row] = acc[i][j][r] + bias[d0 + col];
            }
        __syncthreads();
        const int kbd = kb64 >> 1, parity = kb64 & 1;
        const int cht_l = tid >> 6, lane_s = tid & 63;
        const int l15s = lane_s & 15, lg4s = lane_s >> 4;
        const int cht = (d0 >> 4) + cht_l;
        #pragma unroll
        for (int kc = 0; kc < 4; kc++){
            short tmp[4];
            #pragma unroll
            for (int j = 0; j < 4; j++)
                tmp[j] = f2bf(CT[(cht_l * 16 + l15s) * 65 + kc * 16 + lg4s * 4 + j]);
            size_t base = (size_t)b * 1048576 + (size_t)kbd * 32768 + kc * 8192
                        + cht * 512 + lane_s * 8 + parity * 4;
            *(short4_t*)(Vf + base) = *(short4_t*)tmp;
        }
    }
}

// ---------- K4: flash attention (R2-exact body + register-neutral setprio ONLY):
// 32 queries/wave, lean softmax (defer-max THR=5, per-lane l partials), V staged via
// global_load_lds, next-K reg prefetch, XCD batch affinity, (w,63-w) grid pairing.
// R7 lesson: the 4+4 chain split's extra f32x4 temporaries spilled past the 256-reg
// cliff (WRITE_SIZE 14336->18432 KB). setprio allocates NOTHING (SOPP) — kept alone.
__global__ __launch_bounds__(256, 2) void attn_kernel(const short* __restrict__ Q,
    const short* __restrict__ Kf, const short* __restrict__ Vf,
    short* __restrict__ hb)
{
    __shared__ short SH[4 * 32 * 264];   // 67.6KB: V stage (first 64KB) during loop, LOs after
    __shared__ float mls[4][32][2];

    const int tid = threadIdx.x, lane = tid & 63, kc = tid >> 6;
    const int l15 = lane & 15, lg4 = lane >> 4;
    const int a32 = ((lane ^ 32) << 2);

    const int id  = blockIdx.x;
    const int xcd = id & 7;
    const int b   = xcd >> 1;
    const int hh  = xcd & 1;
    const int r_  = id >> 3;
    const int t_  = r_ & 31;
    const int w   = (r_ & 32) ? 63 - t_ : t_;
    const int q0  = w * 64 + hh * 32;        // tile0: q0+l15, tile1: q0+16+l15

    const short* Kb = Kf + (size_t)b * 1048576 + kc * 4096 + lane * 8;   // +kb*16384 +ks*512
    const short* Vg = Vf + (size_t)b * 1048576 + kc * 8192 + lane * 8;   // per-lane V src
    short* Vl = &SH[kc * 8192];                                          // wave LDS V slice

    // Q as B-fragment (pre-scaled): lane holds Q[q][ks*32+lg4*8 ..+8]
    short8_t qf0[8], qf1[8];
    {
        const short* qp0 = Q + ((size_t)b * 4096 + q0 + l15) * 256;
        const short* qp1 = qp0 + 16 * 256;
        #pragma unroll
        for (int ks = 0; ks < 8; ks++){
            qf0[ks] = *(const short8_t*)(qp0 + ks * 32 + lg4 * 8);
            qf1[ks] = *(const short8_t*)(qp1 + ks * 32 + lg4 * 8);
        }
    }

    f32x4 oacc0[16] = {}, oacc1[16] = {};
    float m0 = -1e30f, l0 = 0.f;             // l0,l1 are PER-LANE partial sums
    float m1 = -1e30f, l1 = 0.f;

    short8_t kf[8];
    #pragma unroll
    for (int ks = 0; ks < 8; ks++) kf[ks] = *(const short8_t*)(Kb + ks * 512);

    for (int kb = 0; kb <= w; kb += 2){
        const bool has_odd = (kb + 1 <= w);

        // strip A QK (kf holds strip kb)
        f32x4 stA0 = {}, stA1 = {};
        __builtin_amdgcn_s_setprio(1);
        #pragma unroll
        for (int ks = 0; ks < 8; ks++){
            stA0 = mfma16(kf[ks], qf0[ks], stA0);
            stA1 = mfma16(kf[ks], qf1[ks], stA1);
        }
        __builtin_amdgcn_s_setprio(0);
        // strip B loads into kf (WAR after stA issue)
        if (has_odd){
            const short* ka = Kb + (size_t)(kb + 1) * 16384;
            #pragma unroll
            for (int ks = 0; ks < 8; ks++) kf[ks] = *(const short8_t*)(ka + ks * 512);
        }
        // V stage for this pair (async -> LDS, newest vmem ops)
        {
            const short* vsrc = Vg + (size_t)(kb >> 1) * 32768;
            #pragma unroll
            for (int i = 0; i < 16; i++)
                gload_lds16(vsrc + i * 512, Vl + i * 512);
        }

        // lean softmax A (covers strip-B load latency)
        f32x4 pA0, pA1;
        {
            float tl0 = fmaxf(fmaxf(stA0[0], stA0[1]), fmaxf(stA0[2], stA0[3]));
            float tl1 = fmaxf(fmaxf(stA1[0], stA1[1]), fmaxf(stA1[2], stA1[3]));
            if (!__all(tl0 <= m0 + 5.f && tl1 <= m1 + 5.f)){
                float tm0 = fmaxf(tl0, swz16(tl0)); tm0 = fmaxf(tm0, bperm32(a32, tm0));
                float tm1 = fmaxf(tl1, swz16(tl1)); tm1 = fmaxf(tm1, bperm32(a32, tm1));
                float mn0 = fmaxf(m0, tm0), mn1 = fmaxf(m1, tm1);
                float al0 = exp2f((m0 - mn0) * LOG2E), al1 = exp2f((m1 - mn1) * LOG2E);
                l0 *= al0; l1 *= al1;
                #pragma unroll
                for (int i = 0; i < 16; i++){
                    #pragma unroll
                    for (int r = 0; r < 4; r++){ oacc0[i][r] *= al0; oacc1[i][r] *= al1; }
                }
                m0 = mn0; m1 = mn1;
            }
            #pragma unroll
            for (int r = 0; r < 4; r++){
                pA0[r] = exp2f((stA0[r] - m0) * LOG2E);
                pA1[r] = exp2f((stA1[r] - m1) * LOG2E);
            }
            l0 += (pA0[0] + pA0[1]) + (pA0[2] + pA0[3]);
            l1 += (pA1[0] + pA1[1]) + (pA1[2] + pA1[3]);
        }

        // strip B QK + next-pair strip-A prefetch + lean softmax B
        f32x4 pB0 = {0.f, 0.f, 0.f, 0.f}, pB1 = {0.f, 0.f, 0.f, 0.f};
        if (has_odd){
            f32x4 stB0 = {}, stB1 = {};
            __builtin_amdgcn_s_setprio(1);
            #pragma unroll
            for (int ks = 0; ks < 8; ks++){
                stB0 = mfma16(kf[ks], qf0[ks], stB0);
                stB1 = mfma16(kf[ks], qf1[ks], stB1);
            }
            __builtin_amdgcn_s_setprio(0);
            if (kb + 2 <= w){
                const short* ka = Kb + (size_t)(kb + 2) * 16384;
                #pragma unroll
                for (int ks = 0; ks < 8; ks++) kf[ks] = *(const short8_t*)(ka + ks * 512);
            }
            float tl0 = fmaxf(fmaxf(stB0[0], stB0[1]), fmaxf(stB0[2], stB0[3]));
            float tl1 = fmaxf(fmaxf(stB1[0], stB1[1]), fmaxf(stB1[2], stB1[3]));
            if (!__all(tl0 <= m0 + 5.f && tl1 <= m1 + 5.f)){
                float tm0 = fmaxf(tl0, swz16(tl0)); tm0 = fmaxf(tm0, bperm32(a32, tm0));
                float tm1 = fmaxf(tl1, swz16(tl1)); tm1 = fmaxf(tm1, bperm32(a32, tm1));
                float mn0 = fmaxf(m0, tm0), mn1 = fmaxf(m1, tm1);
                float al0 = exp2f((m0 - mn0) * LOG2E), al1 = exp2f((m1 - mn1) * LOG2E);
                l0 *= al0; l1 *= al1;
                #pragma unroll
                for (int i = 0; i < 16; i++){
                    #pragma unroll
                    for (int r = 0; r < 4; r++){ oacc0[i][r] *= al0; oacc1[i][r] *= al1; }
                }
                #pragma unroll
                for (int r = 0; r < 4; r++){ pA0[r] *= al0; pA1[r] *= al1; }
                m0 = mn0; m1 = mn1;
            }
            #pragma unroll
            for (int r = 0; r < 4; r++){
                pB0[r] = exp2f((stB0[r] - m0) * LOG2E);
                pB1[r] = exp2f((stB1[r] - m1) * LOG2E);
            }
            l0 += (pB0[0] + pB0[1]) + (pB0[2] + pB0[3]);
            l1 += (pB1[0] + pB1[1]) + (pB1[2] + pB1[3]);
        }

        // pack P^T pair as B-fragment (K=32, key-permuted to match Vf2)
        short pk0[8], pk1[8];
        #pragma unroll
        for (int r = 0; r < 4; r++){
            pk0[r] = f2bf(pA0[r]); pk0[4 + r] = f2bf(pB0[r]);
            pk1[r] = f2bf(pA1[r]); pk1[4 + r] = f2bf(pB1[r]);
        }
        short8_t pbf0 = *(short8_t*)pk0;
        short8_t pbf1 = *(short8_t*)pk1;

        // wait V in LDS: if next-A prefetch (8 loads) is newest, vmcnt(8) drains all V;
        // otherwise nothing was issued after V -> drain fully.
        if (kb + 2 <= w){
            asm volatile("s_waitcnt vmcnt(8)" ::: "memory");
        } else {
            asm volatile("s_waitcnt vmcnt(0)" ::: "memory");
        }
        // PV from LDS (conflict-free linear ds_read_b128)
        __builtin_amdgcn_s_setprio(1);
        #pragma unroll
        for (int cht = 0; cht < 16; cht++){
            short8_t vfr = *(const short8_t*)(Vl + cht * 512 + lane * 8);
            oacc0[cht] = mfma16(vfr, pbf0, oacc0[cht]);
            oacc1[cht] = mfma16(vfr, pbf1, oacc1[cht]);
        }
        __builtin_amdgcn_s_setprio(0);
    }

    // ---- reduce per-lane l partials across the 4 lanes of each query ----
    float l0t = l0 + swz16(l0); l0t += bperm32(a32, l0t);
    float l1t = l1 + swz16(l1); l1t += bperm32(a32, l1t);

    // ---- combine the 4 kc partials ----
    if (lg4 == 0){
        mls[kc][l15][0] = m0;      mls[kc][l15][1] = l0t;
        mls[kc][16 + l15][0] = m1; mls[kc][16 + l15][1] = l1t;
    }
    __syncthreads();
    float sc0, sc1;
    {
        float ms0 = fmaxf(fmaxf(mls[0][l15][0], mls[1][l15][0]),
                          fmaxf(mls[2][l15][0], mls[3][l15][0]));
        float ms1 = fmaxf(fmaxf(mls[0][16 + l15][0], mls[1][16 + l15][0]),
                          fmaxf(mls[2][16 + l15][0], mls[3][16 + l15][0]));
        sc0 = exp2f((m0 - ms0) * LOG2E);
        sc1 = exp2f((m1 - ms1) * LOG2E);
    }
    #pragma unroll
    for (int cht = 0; cht < 16; cht++){
        short t4[4];
        #pragma unroll
        for (int r = 0; r < 4; r++) t4[r] = f2bf(oacc0[cht][r] * sc0);
        *(short4_t*)&SH[((kc * 32) + l15) * 264 + cht * 16 + lg4 * 4] = *(short4_t*)t4;
        #pragma unroll
        for (int r = 0; r < 4; r++) t4[r] = f2bf(oacc1[cht][r] * sc1);
        *(short4_t*)&SH[((kc * 32) + 16 + l15) * 264 + cht * 16 + lg4 * 4] = *(short4_t*)t4;
    }
    __syncthreads();
    // reduce across kc: thread -> (query qq, 32-ch chunk cc)
    {
        const int qq = tid & 31, cc = tid >> 5;
        float mv0 = mls[0][qq][0], mv1 = mls[1][qq][0], mv2 = mls[2][qq][0], mv3 = mls[3][qq][0];
        float ms = fmaxf(fmaxf(mv0, mv1), fmaxf(mv2, mv3));
        float Ls = mls[0][qq][1] * exp2f((mv0 - ms) * LOG2E)
                 + mls[1][qq][1] * exp2f((mv1 - ms) * LOG2E)
                 + mls[2][qq][1] * exp2f((mv2 - ms) * LOG2E)
                 + mls[3][qq][1] * exp2f((mv3 - ms) * LOG2E);
        float inv = 1.f / Ls;
        const int h = hh * 32 + qq;
        short* dst = hb + ((size_t)b * 4096 + h * 64 + w) * 256 + cc * 32;
        #pragma unroll
        for (int c8 = 0; c8 < 4; c8++){
            short8_t a0 = *(const short8_t*)&SH[((0 * 32) + qq) * 264 + cc * 32 + c8 * 8];
            short8_t a1 = *(const short8_t*)&SH[((1 * 32) + qq) * 264 + cc * 32 + c8 * 8];
            short8_t a2 = *(const short8_t*)&SH[((2 * 32) + qq) * 264 + cc * 32 + c8 * 8];
            short8_t a3 = *(const short8_t*)&SH[((3 * 32) + qq) * 264 + cc * 32 + c8 * 8];
            short t8[8];
            #pragma unroll
            for (int j = 0; j < 8; j++){
                float s = (bf2f(a0[j]) + bf2f(a1[j])) + (bf2f(a2[j]) + bf2f(a3[j]));
                t8[j] = f2bf(s * inv);
            }
            *(short8_t*)(dst + c8 * 8) = *(short8_t*)t8;
        }
    }
}

// ---------- K5: final proj + bias + residual (R2-exact split: grid 256x4),
// coalesced f32 store to (B,C,H,W) ----------
__global__ __launch_bounds__(256) void final_gemm(const short* __restrict__ hbuf,
    const short* __restrict__ wT3, const float* __restrict__ b3,
    const float* __restrict__ x, float* __restrict__ out)
{
    __shared__ short As[64 * 72];
    __shared__ short Bs[64 * 72];
    __shared__ float CT[64 * 65];

    const int tid = threadIdx.x;
    const int m0 = blockIdx.x * 64;
    const int d0 = blockIdx.y * 64;
    const int wv = tid >> 6, lane = tid & 63;
    const int wrow = (wv >> 1) * 32, wcol = (wv & 1) * 32;
    const int lrow = lane & 15, lq = lane >> 4;

    f32x4 acc[2][2] = {};
    for (int k0 = 0; k0 < 256; k0 += 64){
        __syncthreads();
        #pragma unroll
        for (int i = 0; i < 2; i++){
            int idx = tid + i * 256, r = idx >> 3, c = (idx & 7) * 8;
            *(short8_t*)&As[r * 72 + c] = *(const short8_t*)(hbuf + (size_t)(m0 + r) * 256 + k0 + c);
            *(short8_t*)&Bs[r * 72 + c] = *(const short8_t*)(wT3 + (size_t)(d0 + r) * 256 + k0 + c);
        }
        __syncthreads();
        #pragma unroll
        for (int kk = 0; kk < 2; kk++){
            int off = kk * 32 + lq * 8;
            short8_t a0  = *(short8_t*)&As[(wrow + lrow) * 72 + off];
            short8_t a1  = *(short8_t*)&As[(wrow + 16 + lrow) * 72 + off];
            short8_t b0v = *(short8_t*)&Bs[(wcol + lrow) * 72 + off];
            short8_t b1v = *(short8_t*)&Bs[(wcol + 16 + lrow) * 72 + off];
            acc[0][0] = mfma16(a0, b0v, acc[0][0]);
            acc[0][1] = mfma16(a0, b1v, acc[0][1]);
            acc[1][0] = mfma16(a1, b0v, acc[1][0]);
            acc[1][1] = mfma16(a1, b1v, acc[1][1]);
        }
    }
    #pragma unroll
    for (int i = 0; i < 2; i++)
      #pragma unroll
      for (int j = 0; j < 2; j++)
        #pragma unroll
        for (int r = 0; r < 4; r++){
            int row = wrow + i * 16 + lq * 4 + r;
            int col = wcol + j * 16 + lrow;
            CT[col * 65 + row] = acc[i][j][r] + b3[d0 + col];
        }
    __syncthreads();
    int b = m0 >> 12, n0 = m0 & 4095, hrow = n0 >> 6;
    int dr = tid >> 2, wc = (tid & 3) * 16;
    size_t base = ((size_t)(b * 256 + d0 + dr) * 64 + hrow) * 64 + wc;
    const f32x4* xp = (const f32x4*)(x + base);
    f32x4* op = (f32x4*)(out + base);
    #pragma unroll
    for (int q = 0; q < 4; q++){
        f32x4 xv = xp[q], o;
        #pragma unroll
        for (int j = 0; j < 4; j++) o[j] = xv[j] + CT[dr * 65 + wc + q * 4 + j];
        op[q] = o;
    }
}

extern "C" void kernel_launch(void* const* d_in, const int* in_sizes, int n_in,
                              void* d_out, int out_size, void* d_ws, size_t ws_size,
                              hipStream_t stream)
{
    const float* x   = (const float*)d_in[0];
    const float* gnw = (const float*)d_in[1];
    const float* gnb = (const float*)d_in[2];
    const float* w0  = (const float*)d_in[3];
    const float* b0  = (const float*)d_in[4];
    const float* w1  = (const float*)d_in[5];
    const float* b1  = (const float*)d_in[6];
    const float* w2  = (const float*)d_in[7];
    const float* b2  = (const float*)d_in[8];
    const float* w3  = (const float*)d_in[9];
    const float* b3  = (const float*)d_in[10];
    float* out = (float*)d_out;

    char* ws = (char*)d_ws;
    short* wT  = (short*)(ws);                  // 512 KB
    short* hn  = (short*)(ws + 524288);         // 8 MB
    short* Qb  = (short*)(ws + 8912896);        // 8 MB
    short* Kfb = (short*)(ws + 17301504);       // frag-major K, 8 MB
    short* Vfb = (short*)(ws + 25690112);       // frag-major V (K=32 perm), 8 MB
    short* hb  = (short*)(ws + 34078720);       // (B, n, C) 8 MB

    prep_gn  <<<2112, 256, 0, stream>>>(w0, w1, w2, w3, wT, x, gnw, gnb, hn);
    qkv_gemm <<<dim3(256, 12), 256, 0, stream>>>(hn, wT, b0, b1, b2, Qb, Kfb, Vfb);
    attn_kernel<<<512, 256, 0, stream>>>(Qb, Kfb, Vfb, hb);
    final_gemm<<<dim3(256, 4), 256, 0, stream>>>(hb, wT + 3 * 65536, b3, x, out);
}

// Round 9
// 196.955 us; speedup vs baseline: 1.1721x; 1.0090x over previous
//
#include <hip/hip_runtime.h>
#include <math.h>

#define LOG2E 1.4426950408889634f

typedef __attribute__((ext_vector_type(8))) __bf16 bf16x8_t;
typedef __attribute__((ext_vector_type(8))) short short8_t;
typedef __attribute__((ext_vector_type(4))) short short4_t;
typedef __attribute__((ext_vector_type(4))) float f32x4;

static __device__ __forceinline__ short f2bf(float f){
    unsigned u = __builtin_bit_cast(unsigned, f);
    unsigned r = (u + 0x7fffu + ((u >> 16) & 1u)) >> 16;
    return (short)r;
}
static __device__ __forceinline__ float bf2f(short s){
    return __builtin_bit_cast(float, (unsigned)((unsigned short)s) << 16);
}

static __device__ __forceinline__ f32x4 mfma16(short8_t a, short8_t b, f32x4 c){
    return __builtin_amdgcn_mfma_f32_16x16x32_bf16(
        __builtin_bit_cast(bf16x8_t, a), __builtin_bit_cast(bf16x8_t, b), c, 0, 0, 0);
}

// xor-lane16 within 32-lane halves (BitMode swizzle), xor-lane32 via bpermute
static __device__ __forceinline__ float swz16(float v){
    return __builtin_bit_cast(float,
        __builtin_amdgcn_ds_swizzle(__builtin_bit_cast(int, v), 0x401F));
}
static __device__ __forceinline__ float bperm32(int addr, float v){
    return __builtin_bit_cast(float,
        __builtin_amdgcn_ds_bpermute(addr, __builtin_bit_cast(int, v)));
}

// async global->LDS, 16B per lane: LDS dest = wave-uniform base + lane*16 (HW),
// global src = per-lane pointer. Our Vf layout is fragment-linear so both match.
static __device__ __forceinline__ void gload_lds16(const void* g, void* l){
    __builtin_amdgcn_global_load_lds(
        (const __attribute__((address_space(1))) unsigned char*)g,
        (__attribute__((address_space(3))) unsigned char*)l, 16, 0, 0);
}

// ---------- K1: fused prep_w + GroupNorm (independent producers, one dispatch). ----------
// Blocks 0..63: weights -> bf16 transposed [mat][d][c] via LDS tile (verbatim R2 prep_w).
// Blocks 64..2111: per-pixel GroupNorm (G=32, 8 ch/group), write hn (B, m~=w*64+h, C) bf16
// (verbatim R2 gn_kernel with bid-64). Disjoint outputs (wT / hn), no mutual deps.
__global__ __launch_bounds__(256) void prep_gn(const float* __restrict__ w0,
    const float* __restrict__ w1, const float* __restrict__ w2,
    const float* __restrict__ w3, short* __restrict__ wT,
    const float* __restrict__ x, const float* __restrict__ gnw,
    const float* __restrict__ gnb, short* __restrict__ hn)
{
    __shared__ float T[64 * 65];
    if (blockIdx.x < 64){
        const int mat = blockIdx.x >> 4, tile = blockIdx.x & 15;
        const int c0 = (tile >> 2) * 64, d0 = (tile & 3) * 64;
        const float* src = mat == 0 ? w0 : mat == 1 ? w1 : mat == 2 ? w2 : w3;
        const int t = threadIdx.x;
        #pragma unroll
        for (int i = 0; i < 4; i++){
            int r = (t >> 4) + i * 16, c4 = (t & 15) * 4;
            f32x4 v = *(const f32x4*)(src + (size_t)(c0 + r) * 256 + d0 + c4);
            #pragma unroll
            for (int j = 0; j < 4; j++) T[r * 65 + c4 + j] = v[j];
        }
        __syncthreads();
        int drow = t >> 2, cb = (t & 3) * 16;
        short tmp[16];
        #pragma unroll
        for (int j = 0; j < 16; j++) tmp[j] = f2bf(T[(cb + j) * 65 + drow]);
        short* dst = wT + (size_t)mat * 65536 + (size_t)(d0 + drow) * 256 + c0 + cb;
        *(short8_t*)dst = *(short8_t*)tmp;
        *(short8_t*)(dst + 8) = *(short8_t*)(tmp + 8);
    } else {
        int flat = (blockIdx.x - 64) * 256 + threadIdx.x;
        int n = flat & 4095, g = (flat >> 12) & 31, b = flat >> 17;
        const float* xp = x + (size_t)(b * 256 + g * 8) * 4096 + n;
        float v[8], s = 0.f, s2 = 0.f;
        #pragma unroll
        for (int k = 0; k < 8; k++){ float t = xp[(size_t)k * 4096]; v[k] = t; s += t; s2 += t * t; }
        float mean = s * 0.125f;
        float var  = s2 * 0.125f - mean * mean;
        float inv  = rsqrtf(var + 1e-6f);
        int h = n >> 6, w = n & 63, m = w * 64 + h;
        short o[8];
        #pragma unroll
        for (int k = 0; k < 8; k++)
            o[k] = f2bf((v[k] - mean) * inv * gnw[g * 8 + k] + gnb[g * 8 + k]);
        *(short8_t*)(hn + (size_t)(b * 4096 + m) * 256 + g * 8) = *(short8_t*)o;
    }
}

// ---------- K3: QKV GEMM (R2-exact split: grid 256x12). Q row-major (pre-scaled 1/16);
// K,V fragment-major.
// Kf[(b,kb64,kc,ks,lane,8)]: lane holds key kc*16+(lane&15), ch ks*32+(lane>>4)*8+j.
// Vf2[(b,kbd,kc,cht,lane,8)]: lane holds ch cht*16+(lane&15); j<4: key kbd*128+kc*16+(lane>>4)*4+j,
//                             j>=4: key kbd*128+64+kc*16+(lane>>4)*4+(j-4).  (K=32 PV permutation)
__global__ __launch_bounds__(256) void qkv_gemm(const short* __restrict__ hn,
    const short* __restrict__ wT, const float* __restrict__ bq,
    const float* __restrict__ bk, const float* __restrict__ bv,
    short* __restrict__ Q, short* __restrict__ Kf, short* __restrict__ Vf)
{
    __shared__ short As[64 * 72];
    __shared__ short Bs[64 * 72];
    __shared__ float CT[64 * 65];

    const int tid = threadIdx.x;
    const int m0 = blockIdx.x * 64;
    const int by = blockIdx.y;
    const int mat = by >> 2;                 // 0=Q 1=K 2=V
    const int d0 = (by & 3) * 64;
    const short* w = wT + mat * 65536;
    const float* bias = mat == 0 ? bq : mat == 1 ? bk : bv;

    const int wv = tid >> 6, lane = tid & 63;
    const int wrow = (wv >> 1) * 32, wcol = (wv & 1) * 32;
    const int lrow = lane & 15, lq = lane >> 4;

    f32x4 acc[2][2] = {};

    for (int k0 = 0; k0 < 256; k0 += 64){
        __syncthreads();
        #pragma unroll
        for (int i = 0; i < 2; i++){
            int idx = tid + i * 256, r = idx >> 3, c = (idx & 7) * 8;
            *(short8_t*)&As[r * 72 + c] = *(const short8_t*)(hn + (size_t)(m0 + r) * 256 + k0 + c);
            *(short8_t*)&Bs[r * 72 + c] = *(const short8_t*)(w  + (size_t)(d0 + r) * 256 + k0 + c);
        }
        __syncthreads();
        #pragma unroll
        for (int kk = 0; kk < 2; kk++){
            int off = kk * 32 + lq * 8;
            short8_t a0  = *(short8_t*)&As[(wrow + lrow) * 72 + off];
            short8_t a1  = *(short8_t*)&As[(wrow + 16 + lrow) * 72 + off];
            short8_t b0v = *(short8_t*)&Bs[(wcol + lrow) * 72 + off];
            short8_t b1v = *(short8_t*)&Bs[(wcol + 16 + lrow) * 72 + off];
            acc[0][0] = mfma16(a0, b0v, acc[0][0]);
            acc[0][1] = mfma16(a0, b1v, acc[0][1]);
            acc[1][0] = mfma16(a1, b0v, acc[1][0]);
            acc[1][1] = mfma16(a1, b1v, acc[1][1]);
        }
    }

    const int b = m0 >> 12, kb64 = (m0 & 4095) >> 6;

    if (mat == 0){
        #pragma unroll
        for (int i = 0; i < 2; i++)
          #pragma unroll
          for (int j = 0; j < 2; j++)
            #pragma unroll
            for (int r = 0; r < 4; r++){
                int row = wrow + i * 16 + lq * 4 + r;
                int col = wcol + j * 16 + lrow;
                Q[(size_t)(m0 + row) * 256 + d0 + col] = f2bf((acc[i][j][r] + bias[d0 + col]) * 0.0625f);
            }
    } else if (mat == 1){
        // CT[key][ch]
        #pragma unroll
        for (int i = 0; i < 2; i++)
          #pragma unroll
          for (int j = 0; j < 2; j++)
            #pragma unroll
            for (int r = 0; r < 4; r++){
                int row = wrow + i * 16 + lq * 4 + r;
                int col = wcol + j * 16 + lrow;
                CT[row * 65 + col] = acc[i][j][r] + bias[d0 + col];
            }
        __syncthreads();
        int key = tid >> 2, c16 = (tid & 3) * 16;
        int kc = key >> 4, l15 = key & 15;
        #pragma unroll
        for (int half = 0; half < 2; half++){
            int ch0 = c16 + half * 8;
            int ks = (d0 + ch0) >> 5, lqf = (ch0 & 31) >> 3;
            short tmp[8];
            #pragma unroll
            for (int j = 0; j < 8; j++) tmp[j] = f2bf(CT[key * 65 + ch0 + j]);
            size_t base = ((((size_t)(b * 64 + kb64)) * 4 + kc) * 8 + ks) * 512 + (lqf * 16 + l15) * 8;
            *(short8_t*)(Kf + base) = *(short8_t*)tmp;
        }
    } else {
        // CT[ch][key]
        #pragma unroll
        for (int i = 0; i < 2; i++)
          #pragma unroll
          for (int j = 0; j < 2; j++)
            #pragma unroll
            for (int r = 0; r < 4; r++){
                int row = wrow + i * 16 + lq * 4 + r;
                int col = wcol + j * 16 + lrow;
                CT[col * 65 + row] = acc[i][j][r] + bias[d0 + col];
            }
        __syncthreads();
        const int kbd = kb64 >> 1, parity = kb64 & 1;
        const int cht_l = tid >> 6, lane_s = tid & 63;
        const int l15s = lane_s & 15, lg4s = lane_s >> 4;
        const int cht = (d0 >> 4) + cht_l;
        #pragma unroll
        for (int kc = 0; kc < 4; kc++){
            short tmp[4];
            #pragma unroll
            for (int j = 0; j < 4; j++)
                tmp[j] = f2bf(CT[(cht_l * 16 + l15s) * 65 + kc * 16 + lg4s * 4 + j]);
            size_t base = (size_t)b * 1048576 + (size_t)kbd * 32768 + kc * 8192
                        + cht * 512 + lane_s * 8 + parity * 4;
            *(short4_t*)(Vf + base) = *(short4_t*)tmp;
        }
    }
}

// ---------- K4: flash attention (R8 body + two register-neutral latency tweaks):
// 32 queries/wave, lean softmax (defer-max THR=5, per-lane l partials), V staged via
// global_load_lds, next-K reg prefetch, XCD batch affinity, (w,63-w) grid pairing,
// setprio around MFMA clusters (R8's banked +6%).
// NEW vs R8 (both allocate nothing — R7's 256-reg cliff lesson):
// (a) nontemporal Q loads + hb stores: stream-once data skips L2 allocation, preserving
//     the exactly-full 4MB/XCD L2 for reused K/V (per-XCD K+V working set = 4MB).
// (b) split V-wait: vmcnt completes in issue order, so after B(8),V(16),A(8) in flight,
//     vmcnt(16) guarantees V0..7 landed -> PV cht 0-7 overlaps V8..15's tail latency,
//     then vmcnt(8) -> cht 8-15. Tail iters: (8)/(0).
__global__ __launch_bounds__(256, 2) void attn_kernel(const short* __restrict__ Q,
    const short* __restrict__ Kf, const short* __restrict__ Vf,
    short* __restrict__ hb)
{
    __shared__ short SH[4 * 32 * 264];   // 67.6KB: V stage (first 64KB) during loop, LOs after
    __shared__ float mls[4][32][2];

    const int tid = threadIdx.x, lane = tid & 63, kc = tid >> 6;
    const int l15 = lane & 15, lg4 = lane >> 4;
    const int a32 = ((lane ^ 32) << 2);

    const int id  = blockIdx.x;
    const int xcd = id & 7;
    const int b   = xcd >> 1;
    const int hh  = xcd & 1;
    const int r_  = id >> 3;
    const int t_  = r_ & 31;
    const int w   = (r_ & 32) ? 63 - t_ : t_;
    const int q0  = w * 64 + hh * 32;        // tile0: q0+l15, tile1: q0+16+l15

    const short* Kb = Kf + (size_t)b * 1048576 + kc * 4096 + lane * 8;   // +kb*16384 +ks*512
    const short* Vg = Vf + (size_t)b * 1048576 + kc * 8192 + lane * 8;   // per-lane V src
    short* Vl = &SH[kc * 8192];                                          // wave LDS V slice

    // Q as B-fragment (pre-scaled): lane holds Q[q][ks*32+lg4*8 ..+8]. Stream-once -> nt.
    short8_t qf0[8], qf1[8];
    {
        const short* qp0 = Q + ((size_t)b * 4096 + q0 + l15) * 256;
        const short* qp1 = qp0 + 16 * 256;
        #pragma unroll
        for (int ks = 0; ks < 8; ks++){
            qf0[ks] = __builtin_nontemporal_load((const short8_t*)(qp0 + ks * 32 + lg4 * 8));
            qf1[ks] = __builtin_nontemporal_load((const short8_t*)(qp1 + ks * 32 + lg4 * 8));
        }
    }

    f32x4 oacc0[16] = {}, oacc1[16] = {};
    float m0 = -1e30f, l0 = 0.f;             // l0,l1 are PER-LANE partial sums
    float m1 = -1e30f, l1 = 0.f;

    short8_t kf[8];
    #pragma unroll
    for (int ks = 0; ks < 8; ks++) kf[ks] = *(const short8_t*)(Kb + ks * 512);

    for (int kb = 0; kb <= w; kb += 2){
        const bool has_odd = (kb + 1 <= w);

        // strip A QK (kf holds strip kb)
        f32x4 stA0 = {}, stA1 = {};
        __builtin_amdgcn_s_setprio(1);
        #pragma unroll
        for (int ks = 0; ks < 8; ks++){
            stA0 = mfma16(kf[ks], qf0[ks], stA0);
            stA1 = mfma16(kf[ks], qf1[ks], stA1);
        }
        __builtin_amdgcn_s_setprio(0);
        // strip B loads into kf (WAR after stA issue)
        if (has_odd){
            const short* ka = Kb + (size_t)(kb + 1) * 16384;
            #pragma unroll
            for (int ks = 0; ks < 8; ks++) kf[ks] = *(const short8_t*)(ka + ks * 512);
        }
        // V stage for this pair (async -> LDS; issued AFTER strip-B K so that QK-B's
        // wait-for-kf (vmcnt(16)) leaves V in flight)
        {
            const short* vsrc = Vg + (size_t)(kb >> 1) * 32768;
            #pragma unroll
            for (int i = 0; i < 16; i++)
                gload_lds16(vsrc + i * 512, Vl + i * 512);
        }

        // lean softmax A (covers strip-B load latency)
        f32x4 pA0, pA1;
        {
            float tl0 = fmaxf(fmaxf(stA0[0], stA0[1]), fmaxf(stA0[2], stA0[3]));
            float tl1 = fmaxf(fmaxf(stA1[0], stA1[1]), fmaxf(stA1[2], stA1[3]));
            if (!__all(tl0 <= m0 + 5.f && tl1 <= m1 + 5.f)){
                float tm0 = fmaxf(tl0, swz16(tl0)); tm0 = fmaxf(tm0, bperm32(a32, tm0));
                float tm1 = fmaxf(tl1, swz16(tl1)); tm1 = fmaxf(tm1, bperm32(a32, tm1));
                float mn0 = fmaxf(m0, tm0), mn1 = fmaxf(m1, tm1);
                float al0 = exp2f((m0 - mn0) * LOG2E), al1 = exp2f((m1 - mn1) * LOG2E);
                l0 *= al0; l1 *= al1;
                #pragma unroll
                for (int i = 0; i < 16; i++){
                    #pragma unroll
                    for (int r = 0; r < 4; r++){ oacc0[i][r] *= al0; oacc1[i][r] *= al1; }
                }
                m0 = mn0; m1 = mn1;
            }
            #pragma unroll
            for (int r = 0; r < 4; r++){
                pA0[r] = exp2f((stA0[r] - m0) * LOG2E);
                pA1[r] = exp2f((stA1[r] - m1) * LOG2E);
            }
            l0 += (pA0[0] + pA0[1]) + (pA0[2] + pA0[3]);
            l1 += (pA1[0] + pA1[1]) + (pA1[2] + pA1[3]);
        }

        // strip B QK + next-pair strip-A prefetch + lean softmax B
        f32x4 pB0 = {0.f, 0.f, 0.f, 0.f}, pB1 = {0.f, 0.f, 0.f, 0.f};
        if (has_odd){
            f32x4 stB0 = {}, stB1 = {};
            __builtin_amdgcn_s_setprio(1);
            #pragma unroll
            for (int ks = 0; ks < 8; ks++){
                stB0 = mfma16(kf[ks], qf0[ks], stB0);
                stB1 = mfma16(kf[ks], qf1[ks], stB1);
            }
            __builtin_amdgcn_s_setprio(0);
            if (kb + 2 <= w){
                const short* ka = Kb + (size_t)(kb + 2) * 16384;
                #pragma unroll
                for (int ks = 0; ks < 8; ks++) kf[ks] = *(const short8_t*)(ka + ks * 512);
            }
            float tl0 = fmaxf(fmaxf(stB0[0], stB0[1]), fmaxf(stB0[2], stB0[3]));
            float tl1 = fmaxf(fmaxf(stB1[0], stB1[1]), fmaxf(stB1[2], stB1[3]));
            if (!__all(tl0 <= m0 + 5.f && tl1 <= m1 + 5.f)){
                float tm0 = fmaxf(tl0, swz16(tl0)); tm0 = fmaxf(tm0, bperm32(a32, tm0));
                float tm1 = fmaxf(tl1, swz16(tl1)); tm1 = fmaxf(tm1, bperm32(a32, tm1));
                float mn0 = fmaxf(m0, tm0), mn1 = fmaxf(m1, tm1);
                float al0 = exp2f((m0 - mn0) * LOG2E), al1 = exp2f((m1 - mn1) * LOG2E);
                l0 *= al0; l1 *= al1;
                #pragma unroll
                for (int i = 0; i < 16; i++){
                    #pragma unroll
                    for (int r = 0; r < 4; r++){ oacc0[i][r] *= al0; oacc1[i][r] *= al1; }
                }
                #pragma unroll
                for (int r = 0; r < 4; r++){ pA0[r] *= al0; pA1[r] *= al1; }
                m0 = mn0; m1 = mn1;
            }
            #pragma unroll
            for (int r = 0; r < 4; r++){
                pB0[r] = exp2f((stB0[r] - m0) * LOG2E);
                pB1[r] = exp2f((stB1[r] - m1) * LOG2E);
            }
            l0 += (pB0[0] + pB0[1]) + (pB0[2] + pB0[3]);
            l1 += (pB1[0] + pB1[1]) + (pB1[2] + pB1[3]);
        }

        // pack P^T pair as B-fragment (K=32, key-permuted to match Vf2)
        short pk0[8], pk1[8];
        #pragma unroll
        for (int r = 0; r < 4; r++){
            pk0[r] = f2bf(pA0[r]); pk0[4 + r] = f2bf(pB0[r]);
            pk1[r] = f2bf(pA1[r]); pk1[4 + r] = f2bf(pB1[r]);
        }
        short8_t pbf0 = *(short8_t*)pk0;
        short8_t pbf1 = *(short8_t*)pk1;

        // Split V-wait (vmcnt is issue-ordered): first half of V done -> PV cht 0-7
        // while V8..15 tail latency hides under MFMAs; then drain second half.
        // Outstanding at this point: [B(8) returned] V(16) [+ A(8) if prefetched].
        if (kb + 2 <= w){
            asm volatile("s_waitcnt vmcnt(16)" ::: "memory");
        } else {
            asm volatile("s_waitcnt vmcnt(8)" ::: "memory");
        }
        __builtin_amdgcn_s_setprio(1);
        #pragma unroll
        for (int cht = 0; cht < 8; cht++){
            short8_t vfr = *(const short8_t*)(Vl + cht * 512 + lane * 8);
            oacc0[cht] = mfma16(vfr, pbf0, oacc0[cht]);
            oacc1[cht] = mfma16(vfr, pbf1, oacc1[cht]);
        }
        if (kb + 2 <= w){
            asm volatile("s_waitcnt vmcnt(8)" ::: "memory");
        } else {
            asm volatile("s_waitcnt vmcnt(0)" ::: "memory");
        }
        #pragma unroll
        for (int cht = 8; cht < 16; cht++){
            short8_t vfr = *(const short8_t*)(Vl + cht * 512 + lane * 8);
            oacc0[cht] = mfma16(vfr, pbf0, oacc0[cht]);
            oacc1[cht] = mfma16(vfr, pbf1, oacc1[cht]);
        }
        __builtin_amdgcn_s_setprio(0);
    }

    // ---- reduce per-lane l partials across the 4 lanes of each query ----
    float l0t = l0 + swz16(l0); l0t += bperm32(a32, l0t);
    float l1t = l1 + swz16(l1); l1t += bperm32(a32, l1t);

    // ---- combine the 4 kc partials ----
    if (lg4 == 0){
        mls[kc][l15][0] = m0;      mls[kc][l15][1] = l0t;
        mls[kc][16 + l15][0] = m1; mls[kc][16 + l15][1] = l1t;
    }
    __syncthreads();
    float sc0, sc1;
    {
        float ms0 = fmaxf(fmaxf(mls[0][l15][0], mls[1][l15][0]),
                          fmaxf(mls[2][l15][0], mls[3][l15][0]));
        float ms1 = fmaxf(fmaxf(mls[0][16 + l15][0], mls[1][16 + l15][0]),
                          fmaxf(mls[2][16 + l15][0], mls[3][16 + l15][0]));
        sc0 = exp2f((m0 - ms0) * LOG2E);
        sc1 = exp2f((m1 - ms1) * LOG2E);
    }
    #pragma unroll
    for (int cht = 0; cht < 16; cht++){
        short t4[4];
        #pragma unroll
        for (int r = 0; r < 4; r++) t4[r] = f2bf(oacc0[cht][r] * sc0);
        *(short4_t*)&SH[((kc * 32) + l15) * 264 + cht * 16 + lg4 * 4] = *(short4_t*)t4;
        #pragma unroll
        for (int r = 0; r < 4; r++) t4[r] = f2bf(oacc1[cht][r] * sc1);
        *(short4_t*)&SH[((kc * 32) + 16 + l15) * 264 + cht * 16 + lg4 * 4] = *(short4_t*)t4;
    }
    __syncthreads();
    // reduce across kc: thread -> (query qq, 32-ch chunk cc); hb is write-once -> nt store
    {
        const int qq = tid & 31, cc = tid >> 5;
        float mv0 = mls[0][qq][0], mv1 = mls[1][qq][0], mv2 = mls[2][qq][0], mv3 = mls[3][qq][0];
        float ms = fmaxf(fmaxf(mv0, mv1), fmaxf(mv2, mv3));
        float Ls = mls[0][qq][1] * exp2f((mv0 - ms) * LOG2E)
                 + mls[1][qq][1] * exp2f((mv1 - ms) * LOG2E)
                 + mls[2][qq][1] * exp2f((mv2 - ms) * LOG2E)
                 + mls[3][qq][1] * exp2f((mv3 - ms) * LOG2E);
        float inv = 1.f / Ls;
        const int h = hh * 32 + qq;
        short* dst = hb + ((size_t)b * 4096 + h * 64 + w) * 256 + cc * 32;
        #pragma unroll
        for (int c8 = 0; c8 < 4; c8++){
            short8_t a0 = *(const short8_t*)&SH[((0 * 32) + qq) * 264 + cc * 32 + c8 * 8];
            short8_t a1 = *(const short8_t*)&SH[((1 * 32) + qq) * 264 + cc * 32 + c8 * 8];
            short8_t a2 = *(const short8_t*)&SH[((2 * 32) + qq) * 264 + cc * 32 + c8 * 8];
            short8_t a3 = *(const short8_t*)&SH[((3 * 32) + qq) * 264 + cc * 32 + c8 * 8];
            short t8[8];
            #pragma unroll
            for (int j = 0; j < 8; j++){
                float s = (bf2f(a0[j]) + bf2f(a1[j])) + (bf2f(a2[j]) + bf2f(a3[j]));
                t8[j] = f2bf(s * inv);
            }
            __builtin_nontemporal_store(*(short8_t*)t8, (short8_t*)(dst + c8 * 8));
        }
    }
}

// ---------- K5: final proj + bias + residual (R2-exact split: grid 256x4),
// coalesced f32 store to (B,C,H,W) ----------
__global__ __launch_bounds__(256) void final_gemm(const short* __restrict__ hbuf,
    const short* __restrict__ wT3, const float* __restrict__ b3,
    const float* __restrict__ x, float* __restrict__ out)
{
    __shared__ short As[64 * 72];
    __shared__ short Bs[64 * 72];
    __shared__ float CT[64 * 65];

    const int tid = threadIdx.x;
    const int m0 = blockIdx.x * 64;
    const int d0 = blockIdx.y * 64;
    const int wv = tid >> 6, lane = tid & 63;
    const int wrow = (wv >> 1) * 32, wcol = (wv & 1) * 32;
    const int lrow = lane & 15, lq = lane >> 4;

    f32x4 acc[2][2] = {};
    for (int k0 = 0; k0 < 256; k0 += 64){
        __syncthreads();
        #pragma unroll
        for (int i = 0; i < 2; i++){
            int idx = tid + i * 256, r = idx >> 3, c = (idx & 7) * 8;
            *(short8_t*)&As[r * 72 + c] = *(const short8_t*)(hbuf + (size_t)(m0 + r) * 256 + k0 + c);
            *(short8_t*)&Bs[r * 72 + c] = *(const short8_t*)(wT3 + (size_t)(d0 + r) * 256 + k0 + c);
        }
        __syncthreads();
        #pragma unroll
        for (int kk = 0; kk < 2; kk++){
            int off = kk * 32 + lq * 8;
            short8_t a0  = *(short8_t*)&As[(wrow + lrow) * 72 + off];
            short8_t a1  = *(short8_t*)&As[(wrow + 16 + lrow) * 72 + off];
            short8_t b0v = *(short8_t*)&Bs[(wcol + lrow) * 72 + off];
            short8_t b1v = *(short8_t*)&Bs[(wcol + 16 + lrow) * 72 + off];
            acc[0][0] = mfma16(a0, b0v, acc[0][0]);
            acc[0][1] = mfma16(a0, b1v, acc[0][1]);
            acc[1][0] = mfma16(a1, b0v, acc[1][0]);
            acc[1][1] = mfma16(a1, b1v, acc[1][1]);
        }
    }
    #pragma unroll
    for (int i = 0; i < 2; i++)
      #pragma unroll
      for (int j = 0; j < 2; j++)
        #pragma unroll
        for (int r = 0; r < 4; r++){
            int row = wrow + i * 16 + lq * 4 + r;
            int col = wcol + j * 16 + lrow;
            CT[col * 65 + row] = acc[i][j][r] + b3[d0 + col];
        }
    __syncthreads();
    int b = m0 >> 12, n0 = m0 & 4095, hrow = n0 >> 6;
    int dr = tid >> 2, wc = (tid & 3) * 16;
    size_t base = ((size_t)(b * 256 + d0 + dr) * 64 + hrow) * 64 + wc;
    const f32x4* xp = (const f32x4*)(x + base);
    f32x4* op = (f32x4*)(out + base);
    #pragma unroll
    for (int q = 0; q < 4; q++){
        f32x4 xv = xp[q], o;
        #pragma unroll
        for (int j = 0; j < 4; j++) o[j] = xv[j] + CT[dr * 65 + wc + q * 4 + j];
        op[q] = o;
    }
}

extern "C" void kernel_launch(void* const* d_in, const int* in_sizes, int n_in,
                              void* d_out, int out_size, void* d_ws, size_t ws_size,
                              hipStream_t stream)
{
    const float* x   = (const float*)d_in[0];
    const float* gnw = (const float*)d_in[1];
    const float* gnb = (const float*)d_in[2];
    const float* w0  = (const float*)d_in[3];
    const float* b0  = (const float*)d_in[4];
    const float* w1  = (const float*)d_in[5];
    const float* b1  = (const float*)d_in[6];
    const float* w2  = (const float*)d_in[7];
    const float* b2  = (const float*)d_in[8];
    const float* w3  = (const float*)d_in[9];
    const float* b3  = (const float*)d_in[10];
    float* out = (float*)d_out;

    char* ws = (char*)d_ws;
    short* wT  = (short*)(ws);                  // 512 KB
    short* hn  = (short*)(ws + 524288);         // 8 MB
    short* Qb  = (short*)(ws + 8912896);        // 8 MB
    short* Kfb = (short*)(ws + 17301504);       // frag-major K, 8 MB
    short* Vfb = (short*)(ws + 25690112);       // frag-major V (K=32 perm), 8 MB
    short* hb  = (short*)(ws + 34078720);       // (B, n, C) 8 MB

    prep_gn  <<<2112, 256, 0, stream>>>(w0, w1, w2, w3, wT, x, gnw, gnb, hn);
    qkv_gemm <<<dim3(256, 12), 256, 0, stream>>>(hn, wT, b0, b1, b2, Qb, Kfb, Vfb);
    attn_kernel<<<512, 256, 0, stream>>>(Qb, Kfb, Vfb, hb);
    final_gemm<<<dim3(256, 4), 256, 0, stream>>>(hb, wT + 3 * 65536, b3, x, out);
}